// Round 1
// baseline (991.046 us; speedup 1.0000x reference)
//
#include <hip/hip_runtime.h>
#include <stdint.h>
#include <stddef.h>

typedef unsigned short u16;
typedef __bf16 bf16_t;
typedef bf16_t bf16x8 __attribute__((ext_vector_type(8)));
typedef float f32x4 __attribute__((ext_vector_type(4)));
typedef u16 u16x4 __attribute__((ext_vector_type(4)));

#define N_NODES 50000
#define N_EDGES 65536
#define D_NODE 1024
#define D_HID 1024

// ---------------- helpers ----------------

__device__ __forceinline__ u16 f2bf(float f) {
  union { float f; uint32_t u; } v; v.f = f;
  uint32_t u = v.u;
  u += 0x7FFF + ((u >> 16) & 1);   // RNE
  return (u16)(u >> 16);
}

typedef __attribute__((address_space(1))) const void GV;
typedef __attribute__((address_space(3))) void LV;

// async global->LDS, 16B per lane; LDS dest = wave-uniform base + lane*16
__device__ __forceinline__ void gll16(const void* g, void* lds_wave_base) {
  __builtin_amdgcn_global_load_lds((GV*)g, (LV*)lds_wave_base, 16, 0, 0);
}

// ---------------- prep kernels ----------------

// probe whether src/dst are int64 (odd dwords all zero) or int32
__global__ void detect_i64_kernel(const int* __restrict__ src, int* __restrict__ flag) {
  if (threadIdx.x == 0 && blockIdx.x == 0) {
    int o = 0;
    for (int i = 1; i < 32; i += 2) o |= src[i];
    *flag = (o == 0) ? 1 : 0;
  }
}

__global__ void cvt_bf16_kernel(const float* __restrict__ in, u16* __restrict__ out, size_t n4) {
  size_t i = (size_t)blockIdx.x * blockDim.x + threadIdx.x;
  if (i >= n4) return;
  float4 v = reinterpret_cast<const float4*>(in)[i];
  u16x4 o;
  o.x = f2bf(v.x); o.y = f2bf(v.y); o.z = f2bf(v.z); o.w = f2bf(v.w);
  reinterpret_cast<u16x4*>(out)[i] = o;
}

// in: [K][N] fp32 row-major  ->  out: [N][K] bf16 row-major
__global__ void transpose_cvt_kernel(const float* __restrict__ in, u16* __restrict__ out,
                                     int K, int N) {
  __shared__ float tile[32][33];
  int n0 = blockIdx.x * 32, k0 = blockIdx.y * 32;
  int tx = threadIdx.x, ty = threadIdx.y;
  #pragma unroll
  for (int i = ty; i < 32; i += 8)
    tile[i][tx] = in[(size_t)(k0 + i) * N + (n0 + tx)];
  __syncthreads();
  #pragma unroll
  for (int i = ty; i < 32; i += 8)
    out[(size_t)(n0 + i) * K + (k0 + tx)] = f2bf(tile[tx][i]);
}

// ---------------- GEMM ----------------
// C[128x128] per block, 256 threads = 4 waves, each wave 64x64 via 4x4 mfma 16x16x32.
// FIRST=true : A row m = concat(nodes[src[m]], nodes[dst[m]]) (bf16, K=2048),
//              epilogue relu -> bf16 store to hout.
// FIRST=false: A = hout bf16 [M][K=1024], epilogue fp32 store to fout.
// Bt: [N][K] bf16 (pre-transposed weights). bias fp32 [N].

template <bool FIRST>
__launch_bounds__(256)
__global__ void gemm_kernel(const u16* __restrict__ Abf,
                            const int* __restrict__ src,
                            const int* __restrict__ dst,
                            const int* __restrict__ is64p,
                            const u16* __restrict__ Bt,
                            const float* __restrict__ bias,
                            u16* __restrict__ hout,
                            float* __restrict__ fout,
                            const int K) {
  __shared__ __align__(16) u16 As[128 * 32];
  __shared__ __align__(16) u16 Bs[128 * 32];

  const int t = threadIdx.x;
  const int lane = t & 63;
  const int wave = t >> 6;
  const int bm = blockIdx.y * 128;
  const int bn = blockIdx.x * 128;
  const int wm = (wave >> 1) * 64;
  const int wn = (wave & 1) * 64;

  // staging coords: thread t covers (row = q*64 + t/4, k = (t&3)*8 .. +8) for issue q
  const int lrow = t >> 2;
  const int kg8 = (t & 3) * 8;

  // A row base pointers (bf16 elements), k-offset kg8 pre-added
  const u16 *a0 = nullptr, *a1 = nullptr, *a0d = nullptr, *a1d = nullptr;
  if (FIRST) {
    const int is64 = *is64p;
    const int e0 = bm + lrow, e1 = bm + 64 + lrow;
    const int s0 = is64 ? src[2 * e0] : src[e0];
    const int s1 = is64 ? src[2 * e1] : src[e1];
    const int d0 = is64 ? dst[2 * e0] : dst[e0];
    const int d1 = is64 ? dst[2 * e1] : dst[e1];
    a0  = Abf + (size_t)s0 * D_NODE + kg8;
    a1  = Abf + (size_t)s1 * D_NODE + kg8;
    a0d = Abf + (size_t)d0 * D_NODE + kg8;
    a1d = Abf + (size_t)d1 * D_NODE + kg8;
  } else {
    a0 = Abf + (size_t)(bm + lrow) * K + kg8;
    a1 = Abf + (size_t)(bm + 64 + lrow) * K + kg8;
  }
  const u16* b0 = Bt + (size_t)(bn + lrow) * K + kg8;
  const u16* b1 = Bt + (size_t)(bn + 64 + lrow) * K + kg8;

  // wave-uniform LDS staging bases (elements): issue q -> q*2048 + wave*512
  u16* ldsA0 = As + wave * 512;
  u16* ldsA1 = As + 2048 + wave * 512;
  u16* ldsB0 = Bs + wave * 512;
  u16* ldsB1 = Bs + 2048 + wave * 512;

  // fragment LDS read pointers (constant across K loop)
  const int lm = lane & 15;
  const int kq = (lane >> 4) * 8;
  const bf16x8* ard[4];
  const bf16x8* brd[4];
  #pragma unroll
  for (int i = 0; i < 4; ++i)
    ard[i] = reinterpret_cast<const bf16x8*>(As + (wm + 16 * i + lm) * 32 + kq);
  #pragma unroll
  for (int j = 0; j < 4; ++j)
    brd[j] = reinterpret_cast<const bf16x8*>(Bs + (wn + 16 * j + lm) * 32 + kq);

  f32x4 acc[4][4] = {};

  const int nsteps = K / 32;
  for (int s = 0; s < nsteps; ++s) {
    const int k0 = s * 32;
    const u16 *pa0, *pa1;
    if (FIRST) {
      if (k0 < D_NODE) { pa0 = a0 + k0;            pa1 = a1 + k0; }
      else             { pa0 = a0d + (k0 - D_NODE); pa1 = a1d + (k0 - D_NODE); }
    } else {
      pa0 = a0 + k0; pa1 = a1 + k0;
    }
    gll16(pa0, ldsA0);
    gll16(pa1, ldsA1);
    gll16(b0 + k0, ldsB0);
    gll16(b1 + k0, ldsB1);
    __syncthreads();

    bf16x8 af[4], bfr[4];
    #pragma unroll
    for (int i = 0; i < 4; ++i) af[i] = *ard[i];
    #pragma unroll
    for (int j = 0; j < 4; ++j) bfr[j] = *brd[j];
    #pragma unroll
    for (int i = 0; i < 4; ++i)
      #pragma unroll
      for (int j = 0; j < 4; ++j)
        acc[i][j] = __builtin_amdgcn_mfma_f32_16x16x32_bf16(af[i], bfr[j], acc[i][j], 0, 0, 0);
    __syncthreads();
  }

  // epilogue: C/D layout col = lane&15, row = (lane>>4)*4 + r
  const int rq = (lane >> 4) * 4;
  #pragma unroll
  for (int j = 0; j < 4; ++j) {
    const int n = bn + wn + 16 * j + lm;
    const float bj = bias[n];
    #pragma unroll
    for (int i = 0; i < 4; ++i) {
      const int m0 = bm + wm + 16 * i + rq;
      f32x4 c = acc[i][j];
      #pragma unroll
      for (int r = 0; r < 4; ++r) {
        float v = c[r] + bj;
        if (FIRST) {
          v = fmaxf(v, 0.0f);
          hout[(size_t)(m0 + r) * D_HID + n] = f2bf(v);
        } else {
          fout[(size_t)(m0 + r) * D_HID + n] = v;
        }
      }
    }
  }
}

// ---------------- launch ----------------

extern "C" void kernel_launch(void* const* d_in, const int* in_sizes, int n_in,
                              void* d_out, int out_size, void* d_ws, size_t ws_size,
                              hipStream_t stream) {
  const float* node_feats = (const float*)d_in[0];
  const int*   src        = (const int*)d_in[1];
  const int*   dst        = (const int*)d_in[2];
  const float* W1         = (const float*)d_in[3];
  const float* b1         = (const float*)d_in[4];
  const float* W2         = (const float*)d_in[5];
  const float* b2         = (const float*)d_in[6];
  float* out = (float*)d_out;

  // workspace layout (bf16 elements)
  u16* ws = (u16*)d_ws;
  const size_t NODE_E = (size_t)N_NODES * D_NODE;       // 51,200,000
  u16* node_bf = ws;
  u16* W1T = node_bf + NODE_E;                          // [1024][2048]
  u16* W2T = W1T + (size_t)2048 * 1024;                 // [1024][1024]
  u16* h   = W2T + (size_t)1024 * 1024;                 // [65536][1024]
  int* flag = (int*)(h + (size_t)N_EDGES * D_HID);

  detect_i64_kernel<<<1, 64, 0, stream>>>(src, flag);

  cvt_bf16_kernel<<<(unsigned)(NODE_E / 4 / 256), 256, 0, stream>>>(node_feats, node_bf, NODE_E / 4);

  transpose_cvt_kernel<<<dim3(1024 / 32, 2048 / 32), dim3(32, 8), 0, stream>>>(W1, W1T, 2048, 1024);
  transpose_cvt_kernel<<<dim3(1024 / 32, 1024 / 32), dim3(32, 8), 0, stream>>>(W2, W2T, 1024, 1024);

  // GEMM1: [65536 x 2048] gathered @ W1T -> relu -> h (bf16)
  gemm_kernel<true><<<dim3(D_HID / 128, N_EDGES / 128), 256, 0, stream>>>(
      node_bf, src, dst, flag, W1T, b1, h, nullptr, 2 * D_NODE);

  // GEMM2: h @ W2T + b2 -> out (fp32)
  gemm_kernel<false><<<dim3(D_HID / 128, N_EDGES / 128), 256, 0, stream>>>(
      h, nullptr, nullptr, nullptr, W2T, b2, nullptr, out, D_HID);
}

// Round 2
// 943.443 us; speedup vs baseline: 1.0505x; 1.0505x over previous
//
#include <hip/hip_runtime.h>
#include <stdint.h>
#include <stddef.h>

typedef unsigned short u16;
typedef __bf16 bf16_t;
typedef bf16_t bf16x8 __attribute__((ext_vector_type(8)));
typedef float f32x4 __attribute__((ext_vector_type(4)));
typedef u16 u16x4 __attribute__((ext_vector_type(4)));

#define N_NODES 50000
#define N_EDGES 65536
#define D_NODE 1024
#define D_HID 1024

// ---------------- helpers ----------------

__device__ __forceinline__ u16 f2bf(float f) {
  union { float f; uint32_t u; } v; v.f = f;
  uint32_t u = v.u;
  u += 0x7FFF + ((u >> 16) & 1);   // RNE
  return (u16)(u >> 16);
}

typedef __attribute__((address_space(1))) const void GV;
typedef __attribute__((address_space(3))) void LV;

// async global->LDS, 16B per lane; LDS dest = wave-uniform base + lane*16
__device__ __forceinline__ void gll16(const void* g, void* lds_wave_base) {
  __builtin_amdgcn_global_load_lds((GV*)g, (LV*)lds_wave_base, 16, 0, 0);
}

// ---------------- prep kernels ----------------

// probe whether src/dst are int64 (odd dwords all zero) or int32
__global__ void detect_i64_kernel(const int* __restrict__ src, int* __restrict__ flag) {
  if (threadIdx.x == 0 && blockIdx.x == 0) {
    int o = 0;
    for (int i = 1; i < 32; i += 2) o |= src[i];
    *flag = (o == 0) ? 1 : 0;
  }
}

__global__ void cvt_bf16_kernel(const float* __restrict__ in, u16* __restrict__ out, size_t n4) {
  size_t i = (size_t)blockIdx.x * blockDim.x + threadIdx.x;
  if (i >= n4) return;
  float4 v = reinterpret_cast<const float4*>(in)[i];
  u16x4 o;
  o.x = f2bf(v.x); o.y = f2bf(v.y); o.z = f2bf(v.z); o.w = f2bf(v.w);
  reinterpret_cast<u16x4*>(out)[i] = o;
}

// in: [K][N] fp32 row-major  ->  out: [N][K] bf16 row-major
__global__ void transpose_cvt_kernel(const float* __restrict__ in, u16* __restrict__ out,
                                     int K, int N) {
  __shared__ float tile[32][33];
  int n0 = blockIdx.x * 32, k0 = blockIdx.y * 32;
  int tx = threadIdx.x, ty = threadIdx.y;
  #pragma unroll
  for (int i = ty; i < 32; i += 8)
    tile[i][tx] = in[(size_t)(k0 + i) * N + (n0 + tx)];
  __syncthreads();
  #pragma unroll
  for (int i = ty; i < 32; i += 8)
    out[(size_t)(n0 + i) * K + (k0 + tx)] = f2bf(tile[tx][i]);
}

// ---------------- GEMM ----------------
// C[128x128] per block, 256 threads = 4 waves, each wave 64x64 via 4x4 mfma 16x16x32.
// Grid is FLAT 4096 blocks; XCD-locality swizzle below keeps the 8 n-tiles of a
// given m-tile (which share the A-tile) on ONE XCD:
//   x = b&7 (XCD under round-robin), r = b>>3, m = x*64 + (r>>3), n = r&7.
//   -> same-m blocks share b%8 AND sit within a 64-id window (robust to both
//      round-robin and chunked workgroup->XCD mappings).
// FIRST=true : A row m = concat(nodes[src[m]], nodes[dst[m]]) (bf16, K=2048),
//              epilogue relu -> bf16 store to hout.
// FIRST=false: A = hout bf16 [M][K=1024], epilogue fp32 store to fout.
// Bt: [N][K] bf16 (pre-transposed weights). bias fp32 [N].

#define MT_PER_XCD 64   // 512 m-tiles / 8 XCDs
#define NT 8            // 1024 / 128 n-tiles

template <bool FIRST>
__launch_bounds__(256)
__global__ void gemm_kernel(const u16* __restrict__ Abf,
                            const int* __restrict__ src,
                            const int* __restrict__ dst,
                            const int* __restrict__ is64p,
                            const u16* __restrict__ Bt,
                            const float* __restrict__ bias,
                            u16* __restrict__ hout,
                            float* __restrict__ fout,
                            const int K) {
  __shared__ __align__(16) u16 As[128 * 32];
  __shared__ __align__(16) u16 Bs[128 * 32];

  const int t = threadIdx.x;
  const int lane = t & 63;
  const int wave = t >> 6;

  // XCD-locality swizzle
  const int b = blockIdx.x;
  const int x = b & 7;
  const int r = b >> 3;
  const int mTile = x * MT_PER_XCD + (r >> 3);
  const int nTile = r & 7;
  const int bm = mTile * 128;
  const int bn = nTile * 128;

  const int wm = (wave >> 1) * 64;
  const int wn = (wave & 1) * 64;

  // staging coords: thread t covers (row = t/4 within 64, k = (t&3)*8 .. +8)
  const int lrow = t >> 2;
  const int kg8 = (t & 3) * 8;

  // A row base pointers (bf16 elements), k-offset kg8 pre-added
  const u16 *a0 = nullptr, *a1 = nullptr, *a0d = nullptr, *a1d = nullptr;
  if (FIRST) {
    const int is64 = *is64p;
    const int e0 = bm + lrow, e1 = bm + 64 + lrow;
    const int s0 = is64 ? src[2 * e0] : src[e0];
    const int s1 = is64 ? src[2 * e1] : src[e1];
    const int d0 = is64 ? dst[2 * e0] : dst[e0];
    const int d1 = is64 ? dst[2 * e1] : dst[e1];
    a0  = Abf + (size_t)s0 * D_NODE + kg8;
    a1  = Abf + (size_t)s1 * D_NODE + kg8;
    a0d = Abf + (size_t)d0 * D_NODE + kg8;
    a1d = Abf + (size_t)d1 * D_NODE + kg8;
  } else {
    a0 = Abf + (size_t)(bm + lrow) * K + kg8;
    a1 = Abf + (size_t)(bm + 64 + lrow) * K + kg8;
  }
  const u16* b0 = Bt + (size_t)(bn + lrow) * K + kg8;
  const u16* b1 = Bt + (size_t)(bn + 64 + lrow) * K + kg8;

  // wave-uniform LDS staging bases (elements): issue q -> q*2048 + wave*512
  u16* ldsA0 = As + wave * 512;
  u16* ldsA1 = As + 2048 + wave * 512;
  u16* ldsB0 = Bs + wave * 512;
  u16* ldsB1 = Bs + 2048 + wave * 512;

  // fragment LDS read pointers (constant across K loop)
  const int lm = lane & 15;
  const int kq = (lane >> 4) * 8;
  const bf16x8* ard[4];
  const bf16x8* brd[4];
  #pragma unroll
  for (int i = 0; i < 4; ++i)
    ard[i] = reinterpret_cast<const bf16x8*>(As + (wm + 16 * i + lm) * 32 + kq);
  #pragma unroll
  for (int j = 0; j < 4; ++j)
    brd[j] = reinterpret_cast<const bf16x8*>(Bs + (wn + 16 * j + lm) * 32 + kq);

  f32x4 acc[4][4] = {};

  const int nsteps = K / 32;
  for (int s = 0; s < nsteps; ++s) {
    const int k0 = s * 32;
    const u16 *pa0, *pa1;
    if (FIRST) {
      if (k0 < D_NODE) { pa0 = a0 + k0;            pa1 = a1 + k0; }
      else             { pa0 = a0d + (k0 - D_NODE); pa1 = a1d + (k0 - D_NODE); }
    } else {
      pa0 = a0 + k0; pa1 = a1 + k0;
    }
    gll16(pa0, ldsA0);
    gll16(pa1, ldsA1);
    gll16(b0 + k0, ldsB0);
    gll16(b1 + k0, ldsB1);
    __syncthreads();

    bf16x8 af[4], bfr[4];
    #pragma unroll
    for (int i = 0; i < 4; ++i) af[i] = *ard[i];
    #pragma unroll
    for (int j = 0; j < 4; ++j) bfr[j] = *brd[j];
    #pragma unroll
    for (int i = 0; i < 4; ++i)
      #pragma unroll
      for (int j = 0; j < 4; ++j)
        acc[i][j] = __builtin_amdgcn_mfma_f32_16x16x32_bf16(af[i], bfr[j], acc[i][j], 0, 0, 0);
    __syncthreads();
  }

  // epilogue: C/D layout col = lane&15, row = (lane>>4)*4 + r
  const int rq = (lane >> 4) * 4;
  #pragma unroll
  for (int j = 0; j < 4; ++j) {
    const int n = bn + wn + 16 * j + lm;
    const float bj = bias[n];
    #pragma unroll
    for (int i = 0; i < 4; ++i) {
      const int m0 = bm + wm + 16 * i + rq;
      f32x4 c = acc[i][j];
      #pragma unroll
      for (int rr = 0; rr < 4; ++rr) {
        float v = c[rr] + bj;
        if (FIRST) {
          v = fmaxf(v, 0.0f);
          hout[(size_t)(m0 + rr) * D_HID + n] = f2bf(v);
        } else {
          fout[(size_t)(m0 + rr) * D_HID + n] = v;
        }
      }
    }
  }
}

// ---------------- launch ----------------

extern "C" void kernel_launch(void* const* d_in, const int* in_sizes, int n_in,
                              void* d_out, int out_size, void* d_ws, size_t ws_size,
                              hipStream_t stream) {
  const float* node_feats = (const float*)d_in[0];
  const int*   src        = (const int*)d_in[1];
  const int*   dst        = (const int*)d_in[2];
  const float* W1         = (const float*)d_in[3];
  const float* b1         = (const float*)d_in[4];
  const float* W2         = (const float*)d_in[5];
  const float* b2         = (const float*)d_in[6];
  float* out = (float*)d_out;

  // workspace layout (bf16 elements)
  u16* ws = (u16*)d_ws;
  const size_t NODE_E = (size_t)N_NODES * D_NODE;       // 51,200,000
  u16* node_bf = ws;
  u16* W1T = node_bf + NODE_E;                          // [1024][2048]
  u16* W2T = W1T + (size_t)2048 * 1024;                 // [1024][1024]
  u16* h   = W2T + (size_t)1024 * 1024;                 // [65536][1024]
  int* flag = (int*)(h + (size_t)N_EDGES * D_HID);

  detect_i64_kernel<<<1, 64, 0, stream>>>(src, flag);

  cvt_bf16_kernel<<<(unsigned)(NODE_E / 4 / 256), 256, 0, stream>>>(node_feats, node_bf, NODE_E / 4);

  transpose_cvt_kernel<<<dim3(1024 / 32, 2048 / 32), dim3(32, 8), 0, stream>>>(W1, W1T, 2048, 1024);
  transpose_cvt_kernel<<<dim3(1024 / 32, 1024 / 32), dim3(32, 8), 0, stream>>>(W2, W2T, 1024, 1024);

  // GEMM1: [65536 x 2048] gathered @ W1T -> relu -> h (bf16)
  gemm_kernel<true><<<4096, 256, 0, stream>>>(
      node_bf, src, dst, flag, W1T, b1, h, nullptr, 2 * D_NODE);

  // GEMM2: h @ W2T + b2 -> out (fp32)
  gemm_kernel<false><<<4096, 256, 0, stream>>>(
      h, nullptr, nullptr, nullptr, W2T, b2, nullptr, out, D_HID);
}